// Round 1
// baseline (1140.594 us; speedup 1.0000x reference)
//
#include <hip/hip_runtime.h>
#include <hip/hip_bf16.h>
#include <math.h>

// Problem constants (B, CIN, COUT, K, S, P, D) = (4,128,128,3,1,1,1), H=W=96
#define HH 96
#define WW 96
#define HW (96*96)
#define CIN_ 128
#define COUT_ 128
#define OMC 27
#define OUT_ELEMS (4*128*96*96)

// ---------------------------------------------------------------------------
// Kernel A: offset/mask conv.  om[b, oc, h, w] = sum_{c,k} wom[oc,c,k] * xpad
// Writes: ws om[b][27][96][96]  (ch 18..26 already sigmoid*2 transformed)
//         d_out offset region   (ch 0..17 raw)
// Grid (3, 48, 4)  block 256 = 4 cin-groups x (2x32 px tile)
// ---------------------------------------------------------------------------
__global__ __launch_bounds__(256) void om_conv_kernel(
    const float* __restrict__ x, const float* __restrict__ wom,
    float* __restrict__ om, float* __restrict__ off_out)
{
    __shared__ float red[4 * 64 * 29];   // 29.7 KB, padded stride 29 (gcd(29,32)=1)

    const int t   = threadIdx.x;
    const int g   = __builtin_amdgcn_readfirstlane(t >> 6);  // cin group, wave-uniform
    const int pxl = t & 63;
    const int r   = pxl >> 5, c = pxl & 31;
    const int b   = blockIdx.z;
    const int h   = blockIdx.y * 2 + r;
    const int w   = blockIdx.x * 32 + c;

    float acc[27];
#pragma unroll
    for (int i = 0; i < 27; i++) acc[i] = 0.f;

    const float* xb = x + (size_t)(b * CIN_) * HW;

    for (int ci = 0; ci < 32; ci++) {           // rolled: uniform counter
        const int cin = g * 32 + ci;
        const float* xc = xb + (size_t)cin * HW;
        float xv[9];
#pragma unroll
        for (int k = 0; k < 9; k++) {
            const int ki = k / 3, kj = k % 3;
            const int y  = h + ki - 1, xx = w + kj - 1;
            const bool v = (y >= 0) && (y < HH) && (xx >= 0) && (xx < WW);
            xv[k] = v ? xc[y * WW + xx] : 0.f;
        }
        const float* wc = wom + (size_t)cin * 9;   // + oc*1152 + k, wave-uniform -> s_load
#pragma unroll
        for (int oc = 0; oc < 27; oc++) {
#pragma unroll
            for (int k = 0; k < 9; k++)
                acc[oc] += wc[(size_t)oc * (CIN_ * 9) + k] * xv[k];
        }
    }

    // reduce across the 4 cin-groups through LDS
#pragma unroll
    for (int oc = 0; oc < 27; oc++) red[(g * 64 + pxl) * 29 + oc] = acc[oc];
    __syncthreads();

    for (int it = t; it < 27 * 64; it += 256) {
        const int oc = it >> 6, p2 = it & 63;
        float s = red[p2 * 29 + oc] + red[(64 + p2) * 29 + oc]
                + red[(128 + p2) * 29 + oc] + red[(192 + p2) * 29 + oc];
        const int r2 = p2 >> 5, c2 = p2 & 31;
        const int gh = blockIdx.y * 2 + r2, gw = blockIdx.x * 32 + c2;
        float outv = s;
        if (oc >= 18) outv = 2.f / (1.f + __expf(-s));   // sigmoid * MASK_SCALE
        om[((size_t)(b * OMC + oc) * HH + gh) * WW + gw] = outv;
        if (oc < 18)
            off_out[((size_t)(b * 18 + oc) * HH + gh) * WW + gw] = s;
    }
}

// ---------------------------------------------------------------------------
// Kernel B: deformable gather + einsum + bias.
// Grid (3, 48, 4)  block 256.  Tile = 2x32 = 64 px.
// Phase 1: per (px, k) item (576): 4 corner idx + mask-scaled bilinear weights.
// Phase 2 (x8 chunks of 16 cin): gather sampled[c][k*64+px] to LDS, then each
//   wave (32 out-channels, wave-uniform) accumulates 32 fp32 acc with SGPR wts.
// ---------------------------------------------------------------------------
#define NC 16

__global__ __launch_bounds__(256, 2) void dconv_kernel(
    const float* __restrict__ x, const float* __restrict__ wt,
    const float* __restrict__ bias, const float* __restrict__ om,
    float* __restrict__ out)
{
    __shared__ int   sidx[4][576];
    __shared__ float swt [4][576];
    __shared__ float smpl[NC][576];   // total LDS 55.3 KB -> 2 blocks/CU

    const int t  = threadIdx.x;
    const int b  = blockIdx.z;
    const int h0 = blockIdx.y * 2, w0 = blockIdx.x * 32;

    // ---- phase 1: sampling prep -------------------------------------------
    for (int s = t; s < 576; s += 256) {
        const int k   = s >> 6;
        const int pxl = s & 63;
        const int r   = pxl >> 5, c = pxl & 31;
        const int h   = h0 + r,   w = w0 + c;
        const int ki  = k / 3,    kj = k % 3;

        const float* omb = om + (size_t)b * OMC * HW + (size_t)h * WW + w;
        const float o1 = omb[(size_t)k * HW];
        const float o2 = omb[(size_t)(9 + k) * HW];
        const float m  = omb[(size_t)(18 + k) * HW];   // already sigmoid*2

        const float py = (float)(h - 1 + ki) + o1;
        const float px = (float)(w - 1 + kj) + o2;
        const float y0f = floorf(py), x0f = floorf(px);
        const float ly = py - y0f,    lx = px - x0f;
        const int y0 = (int)y0f, x0 = (int)x0f;
        const int y1 = y0 + 1,   x1 = x0 + 1;

        const float w00 = (1.f - ly) * (1.f - lx), w01 = (1.f - ly) * lx;
        const float w10 = ly * (1.f - lx),         w11 = ly * lx;

        const int yc0 = min(max(y0, 0), HH - 1), yc1 = min(max(y1, 0), HH - 1);
        const int xc0 = min(max(x0, 0), WW - 1), xc1 = min(max(x1, 0), WW - 1);
        const bool vy0 = (y0 >= 0) && (y0 < HH), vy1 = (y1 >= 0) && (y1 < HH);
        const bool vx0 = (x0 >= 0) && (x0 < WW), vx1 = (x1 >= 0) && (x1 < WW);

        sidx[0][s] = yc0 * WW + xc0;  swt[0][s] = (vy0 && vx0) ? m * w00 : 0.f;
        sidx[1][s] = yc0 * WW + xc1;  swt[1][s] = (vy0 && vx1) ? m * w01 : 0.f;
        sidx[2][s] = yc1 * WW + xc0;  swt[2][s] = (vy1 && vx0) ? m * w10 : 0.f;
        sidx[3][s] = yc1 * WW + xc1;  swt[3][s] = (vy1 && vx1) ? m * w11 : 0.f;
    }
    __syncthreads();

    const int og = __builtin_amdgcn_readfirstlane(t >> 6);  // out-ch group
    const int px = t & 63;

    float acc[32];
#pragma unroll
    for (int i = 0; i < 32; i++) acc[i] = 0.f;

    for (int c0 = 0; c0 < CIN_; c0 += NC) {
        if (c0) __syncthreads();   // smpl reuse: einsum reads done before rewrite

        // ---- gather: 16 ch x 576 items = 9216 = 256 threads x 36 ----------
#pragma unroll 1
        for (int j = 0; j < 36; j++) {
            const int it = j * 256 + t;
            const int c  = it / 576;
            const int s  = it - c * 576;
            const float* xc = x + (size_t)(b * CIN_ + c0 + c) * HW;
            float v = 0.f;
#pragma unroll
            for (int q = 0; q < 4; q++) v += swt[q][s] * xc[sidx[q][s]];
            smpl[c][s] = v;
        }
        __syncthreads();

        // ---- einsum: acc[i] += wt[og*32+i][c0+c][k] * smpl[c][k*64+px] ----
        const float* wb = wt + (size_t)(og * 32) * (CIN_ * 9) + (size_t)c0 * 9;
#pragma unroll 1
        for (int c = 0; c < NC; c++) {
            float sv[9];
#pragma unroll
            for (int k = 0; k < 9; k++) sv[k] = smpl[c][k * 64 + px];
#pragma unroll
            for (int i = 0; i < 32; i++) {
                const float* wr = wb + (size_t)i * (CIN_ * 9) + (size_t)c * 9;
#pragma unroll
                for (int k = 0; k < 9; k++) acc[i] += wr[k] * sv[k];
            }
        }
    }

    // ---- epilogue ---------------------------------------------------------
    const int r = px >> 5, cc = px & 31;
    const int h = h0 + r,  w = w0 + cc;
#pragma unroll
    for (int i = 0; i < 32; i++) {
        const int oc = og * 32 + i;
        out[((size_t)(b * COUT_ + oc) * HH + h) * WW + w] = acc[i] + bias[oc];
    }
}

extern "C" void kernel_launch(void* const* d_in, const int* in_sizes, int n_in,
                              void* d_out, int out_size, void* d_ws, size_t ws_size,
                              hipStream_t stream) {
    const float* x      = (const float*)d_in[0];
    const float* weight = (const float*)d_in[1];
    const float* bias   = (const float*)d_in[2];
    const float* wom    = (const float*)d_in[3];

    float* out     = (float*)d_out;
    float* off_out = out + OUT_ELEMS;          // offset output region
    float* om      = (float*)d_ws;             // [4][27][96][96] = 3.98 MB

    dim3 grid(3, 48, 4);
    om_conv_kernel<<<grid, 256, 0, stream>>>(x, wom, om, off_out);
    dconv_kernel  <<<grid, 256, 0, stream>>>(x, weight, bias, om, out);
}

// Round 2
// 318.517 us; speedup vs baseline: 3.5810x; 3.5810x over previous
//
#include <hip/hip_runtime.h>
#include <hip/hip_bf16.h>
#include <math.h>

// Problem constants (B, CIN, COUT, K, S, P, D) = (4,128,128,3,1,1,1), H=W=96
#define HH 96
#define WW 96
#define HW (96*96)
#define CIN_ 128
#define COUT_ 128
#define OMC 27
#define OUT_ELEMS (4*128*96*96)
#define RS 292   // smpl row stride in bf16 elems: 288 + 4 pad; word-stride 146 -> conflict-free b64 reads

typedef __attribute__((ext_vector_type(8))) short short8v;
typedef __attribute__((ext_vector_type(4))) short short4v;
typedef __attribute__((ext_vector_type(4))) float float4v;

__device__ __forceinline__ short f2bf(float f) {
    unsigned u = __builtin_bit_cast(unsigned, f);
    u += 0x7FFFu + ((u >> 16) & 1u);   // RTN-even (inputs finite)
    return (short)(u >> 16);
}

// ---------------------------------------------------------------------------
// Kernel A: offset/mask conv (unchanged from R1 — profile target next round).
// ---------------------------------------------------------------------------
__global__ __launch_bounds__(256) void om_conv_kernel(
    const float* __restrict__ x, const float* __restrict__ wom,
    float* __restrict__ om, float* __restrict__ off_out)
{
    __shared__ float red[4 * 64 * 29];

    const int t   = threadIdx.x;
    const int g   = __builtin_amdgcn_readfirstlane(t >> 6);
    const int pxl = t & 63;
    const int r   = pxl >> 5, c = pxl & 31;
    const int b   = blockIdx.z;
    const int h   = blockIdx.y * 2 + r;
    const int w   = blockIdx.x * 32 + c;

    float acc[27];
#pragma unroll
    for (int i = 0; i < 27; i++) acc[i] = 0.f;

    const float* xb = x + (size_t)(b * CIN_) * HW;

    for (int ci = 0; ci < 32; ci++) {
        const int cin = g * 32 + ci;
        const float* xc = xb + (size_t)cin * HW;
        float xv[9];
#pragma unroll
        for (int k = 0; k < 9; k++) {
            const int ki = k / 3, kj = k % 3;
            const int y  = h + ki - 1, xx = w + kj - 1;
            const bool v = (y >= 0) && (y < HH) && (xx >= 0) && (xx < WW);
            xv[k] = v ? xc[y * WW + xx] : 0.f;
        }
        const float* wc = wom + (size_t)cin * 9;
#pragma unroll
        for (int oc = 0; oc < 27; oc++) {
#pragma unroll
            for (int k = 0; k < 9; k++)
                acc[oc] += wc[(size_t)oc * (CIN_ * 9) + k] * xv[k];
        }
    }

#pragma unroll
    for (int oc = 0; oc < 27; oc++) red[(g * 64 + pxl) * 29 + oc] = acc[oc];
    __syncthreads();

    for (int it = t; it < 27 * 64; it += 256) {
        const int oc = it >> 6, p2 = it & 63;
        float s = red[p2 * 29 + oc] + red[(64 + p2) * 29 + oc]
                + red[(128 + p2) * 29 + oc] + red[(192 + p2) * 29 + oc];
        const int r2 = p2 >> 5, c2 = p2 & 31;
        const int gh = blockIdx.y * 2 + r2, gw = blockIdx.x * 32 + c2;
        float outv = s;
        if (oc >= 18) outv = 2.f / (1.f + __expf(-s));
        om[((size_t)(b * OMC + oc) * HH + gh) * WW + gw] = outv;
        if (oc < 18)
            off_out[((size_t)(b * 18 + oc) * HH + gh) * WW + gw] = s;
    }
}

// ---------------------------------------------------------------------------
// Weight fp32 -> bf16 (layout already [oc][c*9+k] flat). 147456 elems.
// ---------------------------------------------------------------------------
__global__ __launch_bounds__(256) void wconv_kernel(
    const float* __restrict__ w, short* __restrict__ wb)
{
    const int i = blockIdx.x * 256 + threadIdx.x;
    wb[i] = f2bf(w[i]);
}

// ---------------------------------------------------------------------------
// Kernel B: deformable gather (fp32 -> bf16 LDS) + MFMA einsum + bias.
// Grid (144, 4): 64 consecutive flat pixels per block, all 128 oc.
// 4 waves; wave handles 32 oc (2 m-tiles) x 64 px (4 n-tiles), K=1152 in
// 36 k-steps of mfma_f32_16x16x32_bf16. A-frags from global bf16 weights
// (L2), B-frags from LDS smpl[px][q] (RS=292 -> conflict-free ds_read_b64).
// ---------------------------------------------------------------------------
__global__ __launch_bounds__(256, 2) void dconv_kernel(
    const float* __restrict__ x, const short* __restrict__ wb,
    const float* __restrict__ bias, const float* __restrict__ om,
    float* __restrict__ out)
{
    __shared__ int   sidx[4][576];
    __shared__ float swt [4][576];
    __shared__ short smpl[64 * RS];   // 37376 B; total LDS 55808 -> 2 blocks/CU

    const int t    = threadIdx.x;
    const int wave = __builtin_amdgcn_readfirstlane(t >> 6);
    const int lane = t & 63;
    const int b    = blockIdx.y;
    const int p0   = blockIdx.x * 64;

    // ---- phase 1: sampling prep (per (kc, px) item) -----------------------
    for (int s = t; s < 576; s += 256) {
        const int kc = s >> 6;
        const int px = s & 63;
        const int p  = p0 + px;
        const int h  = p / 96;
        const int w  = p - h * 96;
        const int ki = kc / 3, kj = kc % 3;

        const float* omb = om + (size_t)b * OMC * HW + (size_t)h * WW + w;
        const float o1 = omb[(size_t)kc * HW];
        const float o2 = omb[(size_t)(9 + kc) * HW];
        const float m  = omb[(size_t)(18 + kc) * HW];   // already sigmoid*2

        const float py = (float)(h - 1 + ki) + o1;
        const float px_f = (float)(w - 1 + kj) + o2;
        const float y0f = floorf(py), x0f = floorf(px_f);
        const float ly = py - y0f,    lx = px_f - x0f;
        const int y0 = (int)y0f, x0 = (int)x0f;
        const int y1 = y0 + 1,   x1 = x0 + 1;

        const float w00 = (1.f - ly) * (1.f - lx), w01 = (1.f - ly) * lx;
        const float w10 = ly * (1.f - lx),         w11 = ly * lx;

        const int yc0 = min(max(y0, 0), HH - 1), yc1 = min(max(y1, 0), HH - 1);
        const int xc0 = min(max(x0, 0), WW - 1), xc1 = min(max(x1, 0), WW - 1);
        const bool vy0 = (y0 >= 0) && (y0 < HH), vy1 = (y1 >= 0) && (y1 < HH);
        const bool vx0 = (x0 >= 0) && (x0 < WW), vx1 = (x1 >= 0) && (x1 < WW);

        sidx[0][s] = yc0 * WW + xc0;  swt[0][s] = (vy0 && vx0) ? m * w00 : 0.f;
        sidx[1][s] = yc0 * WW + xc1;  swt[1][s] = (vy0 && vx1) ? m * w01 : 0.f;
        sidx[2][s] = yc1 * WW + xc0;  swt[2][s] = (vy1 && vx0) ? m * w10 : 0.f;
        sidx[3][s] = yc1 * WW + xc1;  swt[3][s] = (vy1 && vx1) ? m * w11 : 0.f;
    }
    __syncthreads();

    float4v acc[2][4];
#pragma unroll
    for (int i = 0; i < 2; i++)
#pragma unroll
        for (int j = 0; j < 4; j++)
#pragma unroll
            for (int r = 0; r < 4; r++) acc[i][j][r] = 0.f;

    const int m    = lane & 15;
    const int quad = lane >> 4;

    for (int ch = 0; ch < 4; ++ch) {   // 4 chunks of 32 cin (288 q each)
        if (ch) __syncthreads();       // smpl reads of prev chunk done

        // ---- gather: q_local = j*4 + wave (uniform), px = lane ------------
        const float* xb = x + ((size_t)b * CIN_ + (size_t)ch * 32) * HW;
#pragma unroll 4
        for (int j = 0; j < 72; ++j) {
            const int ql = j * 4 + wave;
            const int cl = ql / 9;
            const int kc = ql - 9 * cl;
            const float* xc = xb + (size_t)cl * HW;
            const int s = kc * 64 + lane;
            const float v = swt[0][s] * xc[sidx[0][s]]
                          + swt[1][s] * xc[sidx[1][s]]
                          + swt[2][s] * xc[sidx[2][s]]
                          + swt[3][s] * xc[sidx[3][s]];
            smpl[lane * RS + ql] = f2bf(v);
        }
        __syncthreads();

        // ---- MFMA: 9 k-steps x (2 m-tiles x 4 n-tiles) --------------------
        const short* wrow = wb + (size_t)(wave * 32 + m) * 1152 + ch * 288 + quad * 8;
#pragma unroll
        for (int kst = 0; kst < 9; ++kst) {
            const short8v a0 = *(const short8v*)(wrow + kst * 32);
            const short8v a1 = *(const short8v*)(wrow + 16 * 1152 + kst * 32);
            const int qb = kst * 32 + quad * 8;
#pragma unroll
            for (int nt = 0; nt < 4; ++nt) {
                const short* sp = smpl + (nt * 16 + m) * RS + qb;
                const short4v lo = *(const short4v*)sp;
                const short4v hi = *(const short4v*)(sp + 4);
                const short8v bf = __builtin_shufflevector(lo, hi, 0, 1, 2, 3, 4, 5, 6, 7);
                acc[0][nt] = __builtin_amdgcn_mfma_f32_16x16x32_bf16(a0, bf, acc[0][nt], 0, 0, 0);
                acc[1][nt] = __builtin_amdgcn_mfma_f32_16x16x32_bf16(a1, bf, acc[1][nt], 0, 0, 0);
            }
        }
    }

    // ---- epilogue: D col=lane&15 -> px, row=quad*4+r -> oc ----------------
#pragma unroll
    for (int mt = 0; mt < 2; ++mt) {
#pragma unroll
        for (int r = 0; r < 4; ++r) {
            const int oc = wave * 32 + mt * 16 + quad * 4 + r;
            const float bv = bias[oc];
#pragma unroll
            for (int nt = 0; nt < 4; ++nt) {
                out[(size_t)(b * COUT_ + oc) * HW + p0 + nt * 16 + m] = acc[mt][nt][r] + bv;
            }
        }
    }
}

extern "C" void kernel_launch(void* const* d_in, const int* in_sizes, int n_in,
                              void* d_out, int out_size, void* d_ws, size_t ws_size,
                              hipStream_t stream) {
    const float* x      = (const float*)d_in[0];
    const float* weight = (const float*)d_in[1];
    const float* bias   = (const float*)d_in[2];
    const float* wom    = (const float*)d_in[3];

    float* out     = (float*)d_out;
    float* off_out = out + OUT_ELEMS;                 // offset output region
    float* om      = (float*)d_ws;                    // [4][27][96][96] = 3.98 MB
    short* wbf     = (short*)((char*)d_ws + (4u << 20)); // bf16 weights, 288 KB

    om_conv_kernel<<<dim3(3, 48, 4), 256, 0, stream>>>(x, wom, om, off_out);
    wconv_kernel  <<<dim3(576), 256, 0, stream>>>(weight, wbf);
    dconv_kernel  <<<dim3(144, 4), 256, 0, stream>>>(x, wbf, bias, om, out);
}

// Round 3
// 261.216 us; speedup vs baseline: 4.3665x; 1.2194x over previous
//
#include <hip/hip_runtime.h>
#include <hip/hip_bf16.h>
#include <math.h>

// Problem constants (B, CIN, COUT, K, S, P, D) = (4,128,128,3,1,1,1), H=W=96
#define HH 96
#define WW 96
#define HW (96*96)
#define CIN_ 128
#define COUT_ 128
#define OUT_ELEMS (4*128*96*96)

// ws layout (bytes)
#define OM_OFF   0u           // om raw fp32 [4][27][9216] = 3,981,312 B
#define XT_OFF   4194304u     // x_t fp32 [4][9216][128]   = 18,874,368 B
#define WBF_OFF  23068672u    // wbf bf16 [128][1152] (q=kc*128+c) = 294,912 B
#define WOMB_OFF 23363584u    // womb bf16 [32][1152] (q=kc*128+c, rows>=27 zero)

#define BT_STRIDE 68          // btile row stride in dwords (16B-aligned rows)

typedef __attribute__((ext_vector_type(8))) short short8v;
typedef __attribute__((ext_vector_type(4))) float float4v;

__device__ __forceinline__ unsigned short f2bf(float f) {
    unsigned u = __builtin_bit_cast(unsigned, f);
    u += 0x7FFFu + ((u >> 16) & 1u);   // RNE (inputs finite)
    return (unsigned short)(u >> 16);
}

// ---------------------------------------------------------------------------
// x [4][128][9216] fp32  ->  x_t [4][9216][128] fp32.  Grid (144,4), 256 thr.
// ---------------------------------------------------------------------------
__global__ __launch_bounds__(256) void transpose_kernel(
    const float* __restrict__ x, float* __restrict__ xt)
{
    __shared__ float tile[64][130];
    const int t  = threadIdx.x;
    const int b  = blockIdx.y;
    const int p0 = blockIdx.x * 64;

#pragma unroll
    for (int j = 0; j < 8; j++) {               // read: 4 px per thread (float4)
        const int i  = j * 256 + t;
        const int c  = i >> 4;
        const int p4 = (i & 15) * 4;
        const float4 v = *(const float4*)(x + ((size_t)(b * CIN_ + c) * HW + p0 + p4));
        tile[p4 + 0][c] = v.x; tile[p4 + 1][c] = v.y;
        tile[p4 + 2][c] = v.z; tile[p4 + 3][c] = v.w;
    }
    __syncthreads();
#pragma unroll
    for (int j = 0; j < 8; j++) {               // write: 4 c per thread (float4)
        const int i   = j * 256 + t;
        const int pxl = i >> 5;
        const int c4  = (i & 31) * 4;
        float4 v;
        v.x = tile[pxl][c4 + 0]; v.y = tile[pxl][c4 + 1];
        v.z = tile[pxl][c4 + 2]; v.w = tile[pxl][c4 + 3];
        *(float4*)(xt + ((size_t)(b * HW + p0 + pxl) * CIN_ + c4)) = v;
    }
}

// ---------------------------------------------------------------------------
// Weights -> bf16 with q reordered to kc*128+c.  wom padded to 32 rows.
// ---------------------------------------------------------------------------
__global__ __launch_bounds__(256) void wconv_kernel(
    const float* __restrict__ w, const float* __restrict__ wom,
    unsigned short* __restrict__ wbf, unsigned short* __restrict__ womb)
{
    const int i = blockIdx.x * 256 + threadIdx.x;
    if (i < COUT_ * 1152) {
        const int oc = i / 1152, r = i - oc * 1152;
        const int kc = r >> 7, c = r & 127;
        wbf[i] = f2bf(w[(size_t)oc * 1152 + c * 9 + kc]);
    } else {
        const int i2 = i - COUT_ * 1152;
        if (i2 < 32 * 1152) {
            const int row = i2 / 1152, r = i2 - row * 1152;
            const int kc = r >> 7, c = r & 127;
            womb[i2] = (row < 27) ? f2bf(wom[(size_t)row * 1152 + c * 9 + kc]) : 0;
        }
    }
}

// ---------------------------------------------------------------------------
// Offset/mask conv as bf16 MFMA GEMM.  M=32(27 used), K=1152, N=9216 per b.
// Grid (144,4), 256 thr.  Wave = n-tile (16 px) x 32 oc.
// B-tile [64 px][128 c] built per kc from x_t (im2col, coalesced float2).
// Writes raw om to ws + offset channels (0..17) to d_out offset region.
// ---------------------------------------------------------------------------
__global__ __launch_bounds__(256, 2) void om_gemm_kernel(
    const float* __restrict__ xt, const unsigned short* __restrict__ womb,
    float* __restrict__ om, float* __restrict__ off_out)
{
    __shared__ int btile[64 * BT_STRIDE];   // 17408 B

    const int t    = threadIdx.x;
    const int wave = __builtin_amdgcn_readfirstlane(t >> 6);
    const int lane = t & 63;
    const int quad = lane >> 4;
    const int m    = lane & 15;
    const int b    = blockIdx.y;
    const int p0   = blockIdx.x * 64;

    const float* xtb = xt + (size_t)b * HW * CIN_;

    float4v acc[2];
#pragma unroll
    for (int i = 0; i < 2; i++)
#pragma unroll
        for (int r = 0; r < 4; r++) acc[i][r] = 0.f;

    for (int kc = 0; kc < 9; kc++) {
        const int ki = kc / 3, kj = kc - 3 * (kc / 3);
        if (kc) __syncthreads();

        // build im2col B-tile: wave-per-pixel, lanes = 2 channels (float2)
#pragma unroll 4
        for (int p = 0; p < 16; p++) {
            const int pxl = p * 4 + wave;
            const int pg  = p0 + pxl;
            const int h   = pg / 96;
            const int w   = pg - h * 96;
            const int y   = h + ki - 1, xx = w + kj - 1;
            float2 v = make_float2(0.f, 0.f);
            if ((unsigned)y < 96u && (unsigned)xx < 96u)
                v = *(const float2*)(xtb + (size_t)(y * 96 + xx) * CIN_ + 2 * lane);
            btile[pxl * BT_STRIDE + lane] =
                (int)((unsigned)f2bf(v.x) | ((unsigned)f2bf(v.y) << 16));
        }
        __syncthreads();

        const short* bbase = (const short*)btile + (wave * 16 + m) * (BT_STRIDE * 2);
        const short* abase = (const short*)womb + kc * 128 + quad * 8;
#pragma unroll
        for (int kst = 0; kst < 4; kst++) {
            const short8v bf = *(const short8v*)(bbase + kst * 32 + quad * 8);
#pragma unroll
            for (int mt = 0; mt < 2; mt++) {
                const short8v a = *(const short8v*)(abase + (size_t)(mt * 16 + m) * 1152 + kst * 32);
                acc[mt] = __builtin_amdgcn_mfma_f32_16x16x32_bf16(a, bf, acc[mt], 0, 0, 0);
            }
        }
    }

    // epilogue: D col=lane&15 -> px, row=quad*4+r -> oc
#pragma unroll
    for (int mt = 0; mt < 2; mt++) {
#pragma unroll
        for (int r = 0; r < 4; r++) {
            const int oc = mt * 16 + quad * 4 + r;
            const int px = p0 + wave * 16 + m;
            if (oc < 27) om[((size_t)(b * 27 + oc)) * HW + px] = acc[mt][r];
            if (oc < 18) off_out[((size_t)(b * 18 + oc)) * HW + px] = acc[mt][r];
        }
    }
}

// ---------------------------------------------------------------------------
// Main: fused deformable gather (coalesced via x_t) + MFMA GEMM + bias.
// Grid (144,4), 256 thr.  Block: 64 px x 128 oc, K=1152 in 9 kc-chunks.
// Phase 1: 576 items -> sprep LDS (4 corner x_t-row idx + mask-scaled wts).
// Per kc: wave-per-pixel gather (4 coalesced float2 loads/corner-set) ->
// bf16 B-tile [64 px][128 c]; then 32 MFMA (2 mt x 4 nt x 4 kst).
// ---------------------------------------------------------------------------
__global__ __launch_bounds__(256, 2) void dconv_kernel(
    const float* __restrict__ xt, const unsigned short* __restrict__ wbf,
    const float* __restrict__ bias, const float* __restrict__ om,
    float* __restrict__ out)
{
    __shared__ int sprep[576 * 8];          // [s][0..3]=idx, [4..7]=wt bits (18432 B)
    __shared__ int btile[64 * BT_STRIDE];   // 17408 B  (total 35840 B)

    const int t    = threadIdx.x;
    const int wave = __builtin_amdgcn_readfirstlane(t >> 6);
    const int lane = t & 63;
    const int quad = lane >> 4;
    const int m    = lane & 15;
    const int b    = blockIdx.y;
    const int p0   = blockIdx.x * 64;

    // ---- phase 1: sampling prep -------------------------------------------
    for (int s = t; s < 576; s += 256) {
        const int kc  = s >> 6;
        const int pxl = s & 63;
        const int pg  = p0 + pxl;
        const int h   = pg / 96;
        const int w   = pg - h * 96;
        const int ki  = kc / 3, kj = kc - 3 * (kc / 3);

        const float* omb = om + (size_t)b * 27 * HW + pg;
        const float o1 = omb[(size_t)kc * HW];
        const float o2 = omb[(size_t)(9 + kc) * HW];
        const float mr = omb[(size_t)(18 + kc) * HW];
        const float mk = 2.f / (1.f + __expf(-mr));   // sigmoid * MASK_SCALE

        const float py = (float)(h - 1 + ki) + o1;
        const float px = (float)(w - 1 + kj) + o2;
        const float y0f = floorf(py), x0f = floorf(px);
        const float ly = py - y0f,    lx = px - x0f;
        const int y0 = (int)y0f, x0 = (int)x0f;
        const int y1 = y0 + 1,   x1 = x0 + 1;

        const float w00 = (1.f - ly) * (1.f - lx), w01 = (1.f - ly) * lx;
        const float w10 = ly * (1.f - lx),         w11 = ly * lx;

        const int yc0 = min(max(y0, 0), HH - 1), yc1 = min(max(y1, 0), HH - 1);
        const int xc0 = min(max(x0, 0), WW - 1), xc1 = min(max(x1, 0), WW - 1);
        const bool vy0 = (y0 >= 0) && (y0 < HH), vy1 = (y1 >= 0) && (y1 < HH);
        const bool vx0 = (x0 >= 0) && (x0 < WW), vx1 = (x1 >= 0) && (x1 < WW);

        sprep[s * 8 + 0] = yc0 * 96 + xc0;
        sprep[s * 8 + 1] = yc0 * 96 + xc1;
        sprep[s * 8 + 2] = yc1 * 96 + xc0;
        sprep[s * 8 + 3] = yc1 * 96 + xc1;
        sprep[s * 8 + 4] = __builtin_bit_cast(int, (vy0 && vx0) ? mk * w00 : 0.f);
        sprep[s * 8 + 5] = __builtin_bit_cast(int, (vy0 && vx1) ? mk * w01 : 0.f);
        sprep[s * 8 + 6] = __builtin_bit_cast(int, (vy1 && vx0) ? mk * w10 : 0.f);
        sprep[s * 8 + 7] = __builtin_bit_cast(int, (vy1 && vx1) ? mk * w11 : 0.f);
    }
    __syncthreads();

    const float* xtb = xt + (size_t)b * HW * CIN_;

    float4v acc[2][4];
#pragma unroll
    for (int i = 0; i < 2; i++)
#pragma unroll
        for (int j = 0; j < 4; j++)
#pragma unroll
            for (int r = 0; r < 4; r++) acc[i][j][r] = 0.f;

    for (int kc = 0; kc < 9; kc++) {
        if (kc) __syncthreads();

        // ---- gather: wave-per-pixel, lanes = 2 channels (float2) ----------
#pragma unroll 4
        for (int p = 0; p < 16; p++) {
            const int pxl = p * 4 + wave;
            const int s   = kc * 64 + pxl;
            const int4   id4 = *(const int4*)&sprep[s * 8];
            const float4 w4  = *(const float4*)&sprep[s * 8 + 4];
            const float2 c0 = *(const float2*)(xtb + (size_t)id4.x * CIN_ + 2 * lane);
            const float2 c1 = *(const float2*)(xtb + (size_t)id4.y * CIN_ + 2 * lane);
            const float2 c2 = *(const float2*)(xtb + (size_t)id4.z * CIN_ + 2 * lane);
            const float2 c3 = *(const float2*)(xtb + (size_t)id4.w * CIN_ + 2 * lane);
            const float vx = w4.x * c0.x + w4.y * c1.x + w4.z * c2.x + w4.w * c3.x;
            const float vy = w4.x * c0.y + w4.y * c1.y + w4.z * c2.y + w4.w * c3.y;
            btile[pxl * BT_STRIDE + lane] =
                (int)((unsigned)f2bf(vx) | ((unsigned)f2bf(vy) << 16));
        }
        __syncthreads();

        // ---- MFMA: 4 ksteps x (2 mt x 4 nt) -------------------------------
        const short* abase = (const short*)wbf + (size_t)(wave * 32 + m) * 1152 + kc * 128 + quad * 8;
#pragma unroll
        for (int kst = 0; kst < 4; kst++) {
            short8v bfr[4];
#pragma unroll
            for (int nt = 0; nt < 4; nt++)
                bfr[nt] = *(const short8v*)((const short*)btile + (nt * 16 + m) * (BT_STRIDE * 2) + kst * 32 + quad * 8);
#pragma unroll
            for (int mt = 0; mt < 2; mt++) {
                const short8v a = *(const short8v*)(abase + (size_t)mt * 16 * 1152 + kst * 32);
#pragma unroll
                for (int nt = 0; nt < 4; nt++)
                    acc[mt][nt] = __builtin_amdgcn_mfma_f32_16x16x32_bf16(a, bfr[nt], acc[mt][nt], 0, 0, 0);
            }
        }
    }

    // ---- epilogue ---------------------------------------------------------
#pragma unroll
    for (int mt = 0; mt < 2; mt++) {
#pragma unroll
        for (int r = 0; r < 4; r++) {
            const int oc = wave * 32 + mt * 16 + quad * 4 + r;
            const float bv = bias[oc];
#pragma unroll
            for (int nt = 0; nt < 4; nt++)
                out[(size_t)(b * COUT_ + oc) * HW + p0 + nt * 16 + m] = acc[mt][nt][r] + bv;
        }
    }
}

extern "C" void kernel_launch(void* const* d_in, const int* in_sizes, int n_in,
                              void* d_out, int out_size, void* d_ws, size_t ws_size,
                              hipStream_t stream) {
    const float* x      = (const float*)d_in[0];
    const float* weight = (const float*)d_in[1];
    const float* bias   = (const float*)d_in[2];
    const float* wom    = (const float*)d_in[3];

    float* out     = (float*)d_out;
    float* off_out = out + OUT_ELEMS;

    float*          om   = (float*)((char*)d_ws + OM_OFF);
    float*          xt   = (float*)((char*)d_ws + XT_OFF);
    unsigned short* wbf  = (unsigned short*)((char*)d_ws + WBF_OFF);
    unsigned short* womb = (unsigned short*)((char*)d_ws + WOMB_OFF);

    transpose_kernel<<<dim3(144, 4), 256, 0, stream>>>(x, xt);
    wconv_kernel    <<<dim3(720),    256, 0, stream>>>(weight, wom, wbf, womb);
    om_gemm_kernel  <<<dim3(144, 4), 256, 0, stream>>>(xt, womb, om, off_out);
    dconv_kernel    <<<dim3(144, 4), 256, 0, stream>>>(xt, wbf, bias, om, out);
}

// Round 5
// 191.909 us; speedup vs baseline: 5.9434x; 1.3611x over previous
//
#include <hip/hip_runtime.h>
#include <hip/hip_bf16.h>
#include <math.h>

// Problem constants (B, CIN, COUT, K, S, P, D) = (4,128,128,3,1,1,1), H=W=96
#define HH 96
#define WW 96
#define HW (96*96)
#define CIN_ 128
#define COUT_ 128
#define OUT_ELEMS (4*128*96*96)

// ws layout (bytes)
#define XT_OFF   0u           // x_t bf16 [4][9216][128] = 9,437,184 B
#define OM_OFF   9437184u     // om raw fp32 [4][27][9216] = 3,981,312 B
#define WBF_OFF  13418496u    // wbf bf16 [128][1152] (q=kc*128+c) = 294,912 B
#define WOMB_OFF 13713408u    // womb bf16 [32][1152] (q=kc*128+c, rows>=27 zero)

#define BT_STRIDE 68          // btile row stride in dwords (16B-aligned rows)

typedef __attribute__((ext_vector_type(8))) short short8v;
typedef __attribute__((ext_vector_type(4))) float float4v;

__device__ __forceinline__ unsigned short f2bf(float f) {
    unsigned u = __builtin_bit_cast(unsigned, f);
    u += 0x7FFFu + ((u >> 16) & 1u);   // RNE (inputs finite)
    return (unsigned short)(u >> 16);
}
__device__ __forceinline__ float bflo(unsigned u) {
    return __builtin_bit_cast(float, u << 16);
}
__device__ __forceinline__ float bfhi(unsigned u) {
    return __builtin_bit_cast(float, u & 0xffff0000u);
}

// ---------------------------------------------------------------------------
// x [4][128][9216] fp32  ->  x_t [4][9216][128] bf16.  Grid (144,4), 256 thr.
// ---------------------------------------------------------------------------
__global__ __launch_bounds__(256) void transpose_kernel(
    const float* __restrict__ x, unsigned short* __restrict__ xt)
{
    __shared__ float tile[64][130];
    const int t  = threadIdx.x;
    const int b  = blockIdx.y;
    const int p0 = blockIdx.x * 64;

#pragma unroll
    for (int j = 0; j < 8; j++) {               // read: 4 px per thread (float4)
        const int i  = j * 256 + t;
        const int c  = i >> 4;
        const int p4 = (i & 15) * 4;
        const float4 v = *(const float4*)(x + ((size_t)(b * CIN_ + c) * HW + p0 + p4));
        tile[p4 + 0][c] = v.x; tile[p4 + 1][c] = v.y;
        tile[p4 + 2][c] = v.z; tile[p4 + 3][c] = v.w;
    }
    __syncthreads();
#pragma unroll
    for (int j = 0; j < 8; j++) {               // write: 4 c per thread (8 B bf16)
        const int i   = j * 256 + t;
        const int pxl = i >> 5;
        const int c4  = (i & 31) * 4;
        uint2 v;
        v.x = (unsigned)f2bf(tile[pxl][c4 + 0]) | ((unsigned)f2bf(tile[pxl][c4 + 1]) << 16);
        v.y = (unsigned)f2bf(tile[pxl][c4 + 2]) | ((unsigned)f2bf(tile[pxl][c4 + 3]) << 16);
        *(uint2*)(xt + ((size_t)(b * HW + p0 + pxl) * CIN_ + c4)) = v;
    }
}

// ---------------------------------------------------------------------------
// Weights -> bf16 with q reordered to kc*128+c.  wom padded to 32 rows.
// ---------------------------------------------------------------------------
__global__ __launch_bounds__(256) void wconv_kernel(
    const float* __restrict__ w, const float* __restrict__ wom,
    unsigned short* __restrict__ wbf, unsigned short* __restrict__ womb)
{
    const int i = blockIdx.x * 256 + threadIdx.x;
    if (i < COUT_ * 1152) {
        const int oc = i / 1152, r = i - oc * 1152;
        const int kc = r >> 7, c = r & 127;
        wbf[i] = f2bf(w[(size_t)oc * 1152 + c * 9 + kc]);
    } else {
        const int i2 = i - COUT_ * 1152;
        if (i2 < 32 * 1152) {
            const int row = i2 / 1152, r = i2 - row * 1152;
            const int kc = r >> 7, c = r & 127;
            womb[i2] = (row < 27) ? f2bf(wom[(size_t)row * 1152 + c * 9 + kc]) : 0;
        }
    }
}

// ---------------------------------------------------------------------------
// Offset/mask conv as bf16 MFMA GEMM.  M=32(27 used), K=1152, N=9216 per b.
// Grid (144,4), 256 thr.  Wave = n-tile (16 px) x 32 oc.
// B-tile [64 px][128 c] built per kc from bf16 x_t (im2col = pure copy).
// Writes raw om to ws + offset channels (0..17) to d_out offset region.
// ---------------------------------------------------------------------------
__global__ __launch_bounds__(256, 2) void om_gemm_kernel(
    const unsigned short* __restrict__ xt, const unsigned short* __restrict__ womb,
    float* __restrict__ om, float* __restrict__ off_out)
{
    __shared__ int btile[64 * BT_STRIDE];   // 17408 B

    const int t    = threadIdx.x;
    const int wave = __builtin_amdgcn_readfirstlane(t >> 6);
    const int lane = t & 63;
    const int quad = lane >> 4;
    const int m    = lane & 15;
    const int b    = blockIdx.y;
    const int p0   = blockIdx.x * 64;

    const unsigned short* xtb = xt + (size_t)b * HW * CIN_;

    float4v acc[2];
#pragma unroll
    for (int i = 0; i < 2; i++)
#pragma unroll
        for (int r = 0; r < 4; r++) acc[i][r] = 0.f;

    for (int kc = 0; kc < 9; kc++) {
        const int ki = kc / 3, kj = kc - 3 * (kc / 3);
        if (kc) __syncthreads();

        // build im2col B-tile: wave-per-pixel, lanes = 2 channels (int copy)
#pragma unroll 4
        for (int p = 0; p < 16; p++) {
            const int pxl = p * 4 + wave;
            const int pg  = p0 + pxl;
            const int h   = pg / 96;
            const int w   = pg - h * 96;
            const int y   = h + ki - 1, xx = w + kj - 1;
            int v = 0;
            if ((unsigned)y < 96u && (unsigned)xx < 96u)
                v = *(const int*)(xtb + (size_t)(y * 96 + xx) * CIN_ + 2 * lane);
            btile[pxl * BT_STRIDE + lane] = v;
        }
        __syncthreads();

        const short* bbase = (const short*)btile + (wave * 16 + m) * (BT_STRIDE * 2);
        const short* abase = (const short*)womb + kc * 128 + quad * 8;
#pragma unroll
        for (int kst = 0; kst < 4; kst++) {
            const short8v bf = *(const short8v*)(bbase + kst * 32 + quad * 8);
#pragma unroll
            for (int mt = 0; mt < 2; mt++) {
                const short8v a = *(const short8v*)(abase + (size_t)(mt * 16 + m) * 1152 + kst * 32);
                acc[mt] = __builtin_amdgcn_mfma_f32_16x16x32_bf16(a, bf, acc[mt], 0, 0, 0);
            }
        }
    }

    // epilogue: D col=lane&15 -> px, row=quad*4+r -> oc
#pragma unroll
    for (int mt = 0; mt < 2; mt++) {
#pragma unroll
        for (int r = 0; r < 4; r++) {
            const int oc = mt * 16 + quad * 4 + r;
            const int px = p0 + wave * 16 + m;
            if (oc < 27) om[((size_t)(b * 27 + oc)) * HW + px] = acc[mt][r];
            if (oc < 18) off_out[((size_t)(b * 18 + oc)) * HW + px] = acc[mt][r];
        }
    }
}

// ---------------------------------------------------------------------------
// Main: fused deformable gather (coalesced via bf16 x_t) + MFMA GEMM + bias.
// Grid (144,4), 256 thr.  Block: 64 px x 128 oc, K=1152 in 9 kc-chunks.
// Identical to R3 structure; only the corner loads are bf16 (4 B/lane).
// ---------------------------------------------------------------------------
__global__ __launch_bounds__(256, 2) void dconv_kernel(
    const unsigned short* __restrict__ xt, const unsigned short* __restrict__ wbf,
    const float* __restrict__ bias, const float* __restrict__ om,
    float* __restrict__ out)
{
    __shared__ int sprep[576 * 8];          // 18432 B
    __shared__ int btile[64 * BT_STRIDE];   // 17408 B  (total 35840 B)

    const int t    = threadIdx.x;
    const int wave = __builtin_amdgcn_readfirstlane(t >> 6);
    const int lane = t & 63;
    const int quad = lane >> 4;
    const int m    = lane & 15;
    const int b    = blockIdx.y;
    const int p0   = blockIdx.x * 64;

    // ---- phase 1: sampling prep -------------------------------------------
    for (int s = t; s < 576; s += 256) {
        const int kc  = s >> 6;
        const int pxl = s & 63;
        const int pg  = p0 + pxl;
        const int h   = pg / 96;
        const int w   = pg - h * 96;
        const int ki  = kc / 3, kj = kc - 3 * (kc / 3);

        const float* omb = om + (size_t)b * 27 * HW + pg;
        const float o1 = omb[(size_t)kc * HW];
        const float o2 = omb[(size_t)(9 + kc) * HW];
        const float mr = omb[(size_t)(18 + kc) * HW];
        const float mk = 2.f / (1.f + __expf(-mr));   // sigmoid * MASK_SCALE

        const float py = (float)(h - 1 + ki) + o1;
        const float px = (float)(w - 1 + kj) + o2;
        const float y0f = floorf(py), x0f = floorf(px);
        const float ly = py - y0f,    lx = px - x0f;
        const int y0 = (int)y0f, x0 = (int)x0f;
        const int y1 = y0 + 1,   x1 = x0 + 1;

        const float w00 = (1.f - ly) * (1.f - lx), w01 = (1.f - ly) * lx;
        const float w10 = ly * (1.f - lx),         w11 = ly * lx;

        const int yc0 = min(max(y0, 0), HH - 1), yc1 = min(max(y1, 0), HH - 1);
        const int xc0 = min(max(x0, 0), WW - 1), xc1 = min(max(x1, 0), WW - 1);
        const bool vy0 = (y0 >= 0) && (y0 < HH), vy1 = (y1 >= 0) && (y1 < HH);
        const bool vx0 = (x0 >= 0) && (x0 < WW), vx1 = (x1 >= 0) && (x1 < WW);

        sprep[s * 8 + 0] = yc0 * 96 + xc0;
        sprep[s * 8 + 1] = yc0 * 96 + xc1;
        sprep[s * 8 + 2] = yc1 * 96 + xc0;
        sprep[s * 8 + 3] = yc1 * 96 + xc1;
        sprep[s * 8 + 4] = __builtin_bit_cast(int, (vy0 && vx0) ? mk * w00 : 0.f);
        sprep[s * 8 + 5] = __builtin_bit_cast(int, (vy0 && vx1) ? mk * w01 : 0.f);
        sprep[s * 8 + 6] = __builtin_bit_cast(int, (vy1 && vx0) ? mk * w10 : 0.f);
        sprep[s * 8 + 7] = __builtin_bit_cast(int, (vy1 && vx1) ? mk * w11 : 0.f);
    }
    __syncthreads();

    const unsigned short* xtb = xt + (size_t)b * HW * CIN_;

    float4v acc[2][4];
#pragma unroll
    for (int i = 0; i < 2; i++)
#pragma unroll
        for (int j = 0; j < 4; j++)
#pragma unroll
            for (int r = 0; r < 4; r++) acc[i][j][r] = 0.f;

    for (int kc = 0; kc < 9; kc++) {
        if (kc) __syncthreads();

        // ---- gather: wave-per-pixel, lane = 2 channels (bf16 pair = 4 B) --
#pragma unroll 4
        for (int p = 0; p < 16; p++) {
            const int pxl = p * 4 + wave;
            const int s   = kc * 64 + pxl;
            const int4   id4 = *(const int4*)&sprep[s * 8];
            const float4 w4  = *(const float4*)&sprep[s * 8 + 4];
            const unsigned u0 = *(const unsigned*)(xtb + (size_t)id4.x * CIN_ + 2 * lane);
            const unsigned u1 = *(const unsigned*)(xtb + (size_t)id4.y * CIN_ + 2 * lane);
            const unsigned u2 = *(const unsigned*)(xtb + (size_t)id4.z * CIN_ + 2 * lane);
            const unsigned u3 = *(const unsigned*)(xtb + (size_t)id4.w * CIN_ + 2 * lane);
            const float vx = w4.x * bflo(u0) + w4.y * bflo(u1) + w4.z * bflo(u2) + w4.w * bflo(u3);
            const float vy = w4.x * bfhi(u0) + w4.y * bfhi(u1) + w4.z * bfhi(u2) + w4.w * bfhi(u3);
            btile[pxl * BT_STRIDE + lane] =
                (int)((unsigned)f2bf(vx) | ((unsigned)f2bf(vy) << 16));
        }
        __syncthreads();

        // ---- MFMA: 4 ksteps x (2 mt x 4 nt) -------------------------------
        const short* abase = (const short*)wbf + (size_t)(wave * 32 + m) * 1152 + kc * 128 + quad * 8;
#pragma unroll
        for (int kst = 0; kst < 4; kst++) {
            short8v bfr[4];
#pragma unroll
            for (int nt = 0; nt < 4; nt++)
                bfr[nt] = *(const short8v*)((const short*)btile + (nt * 16 + m) * (BT_STRIDE * 2) + kst * 32 + quad * 8);
#pragma unroll
            for (int mt = 0; mt < 2; mt++) {
                const short8v a = *(const short8v*)(abase + (size_t)mt * 16 * 1152 + kst * 32);
#pragma unroll
                for (int nt = 0; nt < 4; nt++)
                    acc[mt][nt] = __builtin_amdgcn_mfma_f32_16x16x32_bf16(a, bfr[nt], acc[mt][nt], 0, 0, 0);
            }
        }
    }

    // ---- epilogue ---------------------------------------------------------
#pragma unroll
    for (int mt = 0; mt < 2; mt++) {
#pragma unroll
        for (int r = 0; r < 4; r++) {
            const int oc = wave * 32 + mt * 16 + quad * 4 + r;
            const float bv = bias[oc];
#pragma unroll
            for (int nt = 0; nt < 4; nt++)
                out[(size_t)(b * COUT_ + oc) * HW + p0 + nt * 16 + m] = acc[mt][nt][r] + bv;
        }
    }
}

extern "C" void kernel_launch(void* const* d_in, const int* in_sizes, int n_in,
                              void* d_out, int out_size, void* d_ws, size_t ws_size,
                              hipStream_t stream) {
    const float* x      = (const float*)d_in[0];
    const float* weight = (const float*)d_in[1];
    const float* bias   = (const float*)d_in[2];
    const float* wom    = (const float*)d_in[3];

    float* out     = (float*)d_out;
    float* off_out = out + OUT_ELEMS;

    unsigned short* xtb  = (unsigned short*)((char*)d_ws + XT_OFF);
    float*          om   = (float*)((char*)d_ws + OM_OFF);
    unsigned short* wbf  = (unsigned short*)((char*)d_ws + WBF_OFF);
    unsigned short* womb = (unsigned short*)((char*)d_ws + WOMB_OFF);

    transpose_kernel<<<dim3(144, 4), 256, 0, stream>>>(x, xtb);
    wconv_kernel    <<<dim3(720),    256, 0, stream>>>(weight, wom, wbf, womb);
    om_gemm_kernel  <<<dim3(144, 4), 256, 0, stream>>>(xtb, womb, om, off_out);
    dconv_kernel    <<<dim3(144, 4), 256, 0, stream>>>(xtb, wbf, bias, om, out);
}

// Round 6
// 176.459 us; speedup vs baseline: 6.4638x; 1.0876x over previous
//
#include <hip/hip_runtime.h>
#include <hip/hip_bf16.h>
#include <math.h>

// Problem constants (B, CIN, COUT, K, S, P, D) = (4,128,128,3,1,1,1), H=W=96
#define HH 96
#define WW 96
#define HW (96*96)
#define CIN_ 128
#define COUT_ 128
#define OUT_ELEMS (4*128*96*96)

// ws layout (bytes)
#define XT_OFF   0u           // x_t bf16 [4][9216][128] = 9,437,184 B
#define OM_OFF   9437184u     // om raw fp32 [4][27][9216] = 3,981,312 B
#define WBF_OFF  13418496u    // wbf bf16 [128][1152] (q=kc*128+c) = 294,912 B
#define WOMB_OFF 13713408u    // womb bf16 [32][1152] (q=kc*128+c, rows>=27 zero)

#define BT_STRIDE 68          // btile row stride in dwords (16B-aligned rows)

typedef __attribute__((ext_vector_type(8))) short short8v;
typedef __attribute__((ext_vector_type(4))) float float4v;

__device__ __forceinline__ unsigned short f2bf(float f) {
    unsigned u = __builtin_bit_cast(unsigned, f);
    u += 0x7FFFu + ((u >> 16) & 1u);   // RNE (inputs finite)
    return (unsigned short)(u >> 16);
}
__device__ __forceinline__ float bflo(unsigned u) {
    return __builtin_bit_cast(float, u << 16);
}
__device__ __forceinline__ float bfhi(unsigned u) {
    return __builtin_bit_cast(float, u & 0xffff0000u);
}

// ---------------------------------------------------------------------------
// x [4][128][9216] fp32  ->  x_t [4][9216][128] bf16.  Grid (144,4), 256 thr.
// ---------------------------------------------------------------------------
__global__ __launch_bounds__(256) void transpose_kernel(
    const float* __restrict__ x, unsigned short* __restrict__ xt)
{
    __shared__ float tile[64][130];
    const int t  = threadIdx.x;
    const int b  = blockIdx.y;
    const int p0 = blockIdx.x * 64;

#pragma unroll
    for (int j = 0; j < 8; j++) {               // read: 4 px per thread (float4)
        const int i  = j * 256 + t;
        const int c  = i >> 4;
        const int p4 = (i & 15) * 4;
        const float4 v = *(const float4*)(x + ((size_t)(b * CIN_ + c) * HW + p0 + p4));
        tile[p4 + 0][c] = v.x; tile[p4 + 1][c] = v.y;
        tile[p4 + 2][c] = v.z; tile[p4 + 3][c] = v.w;
    }
    __syncthreads();
#pragma unroll
    for (int j = 0; j < 8; j++) {               // write: 4 c per thread (8 B bf16)
        const int i   = j * 256 + t;
        const int pxl = i >> 5;
        const int c4  = (i & 31) * 4;
        uint2 v;
        v.x = (unsigned)f2bf(tile[pxl][c4 + 0]) | ((unsigned)f2bf(tile[pxl][c4 + 1]) << 16);
        v.y = (unsigned)f2bf(tile[pxl][c4 + 2]) | ((unsigned)f2bf(tile[pxl][c4 + 3]) << 16);
        *(uint2*)(xt + ((size_t)(b * HW + p0 + pxl) * CIN_ + c4)) = v;
    }
}

// ---------------------------------------------------------------------------
// Weights -> bf16 with q reordered to kc*128+c.  wom padded to 32 rows.
// ---------------------------------------------------------------------------
__global__ __launch_bounds__(256) void wconv_kernel(
    const float* __restrict__ w, const float* __restrict__ wom,
    unsigned short* __restrict__ wbf, unsigned short* __restrict__ womb)
{
    const int i = blockIdx.x * 256 + threadIdx.x;
    if (i < COUT_ * 1152) {
        const int oc = i / 1152, r = i - oc * 1152;
        const int kc = r >> 7, c = r & 127;
        wbf[i] = f2bf(w[(size_t)oc * 1152 + c * 9 + kc]);
    } else {
        const int i2 = i - COUT_ * 1152;
        if (i2 < 32 * 1152) {
            const int row = i2 / 1152, r = i2 - row * 1152;
            const int kc = r >> 7, c = r & 127;
            womb[i2] = (row < 27) ? f2bf(wom[(size_t)row * 1152 + c * 9 + kc]) : 0;
        }
    }
}

// ---------------------------------------------------------------------------
// Offset/mask conv as bf16 MFMA GEMM — LDS-free.  M=32(27), K=1152, N=9216/b.
// Grid (144,4), 256 thr.  Wave = 16-px n-tile (wave*16+m), 2 m-tiles.
// B-frags loaded DIRECTLY from x_t (16 contiguous bytes/lane, per-lane
// border predication); A-frags direct from womb (L1-hot).  No syncthreads.
// ---------------------------------------------------------------------------
__global__ __launch_bounds__(256) void om_gemm_kernel(
    const unsigned short* __restrict__ xt, const unsigned short* __restrict__ womb,
    float* __restrict__ om, float* __restrict__ off_out)
{
    const int t    = threadIdx.x;
    const int wave = __builtin_amdgcn_readfirstlane(t >> 6);
    const int lane = t & 63;
    const int quad = lane >> 4;
    const int m    = lane & 15;
    const int b    = blockIdx.y;
    const int p0   = blockIdx.x * 64;

    const unsigned short* xtb = xt + (size_t)b * HW * CIN_;

    // this lane's pixel (B-fragment n-index)
    const int pg = p0 + wave * 16 + m;
    const int h  = pg / 96;
    const int w  = pg - h * 96;

    float4v acc[2];
#pragma unroll
    for (int i = 0; i < 2; i++)
#pragma unroll
        for (int r = 0; r < 4; r++) acc[i][r] = 0.f;

    const short8v zerov = (short8v)0;

#pragma unroll
    for (int kc = 0; kc < 9; kc++) {
        const int ki = kc / 3, kj = kc - 3 * (kc / 3);
        const int y  = h + ki - 1, xx = w + kj - 1;
        const bool valid = ((unsigned)y < 96u) && ((unsigned)xx < 96u);
        const unsigned short* brow = xtb + (size_t)(y * 96 + xx) * CIN_ + quad * 8;
        const short* abase = (const short*)womb + kc * 128 + quad * 8;
#pragma unroll
        for (int kst = 0; kst < 4; kst++) {
            const short8v bf = valid ? *(const short8v*)(brow + kst * 32) : zerov;
#pragma unroll
            for (int mt = 0; mt < 2; mt++) {
                const short8v a = *(const short8v*)(abase + (size_t)(mt * 16 + m) * 1152 + kst * 32);
                acc[mt] = __builtin_amdgcn_mfma_f32_16x16x32_bf16(a, bf, acc[mt], 0, 0, 0);
            }
        }
    }

    // epilogue: D col=lane&15 -> px, row=quad*4+r -> oc
#pragma unroll
    for (int mt = 0; mt < 2; mt++) {
#pragma unroll
        for (int r = 0; r < 4; r++) {
            const int oc = mt * 16 + quad * 4 + r;
            const int px = p0 + wave * 16 + m;
            if (oc < 27) om[((size_t)(b * 27 + oc)) * HW + px] = acc[mt][r];
            if (oc < 18) off_out[((size_t)(b * 18 + oc)) * HW + px] = acc[mt][r];
        }
    }
}

// ---------------------------------------------------------------------------
// Main: deformable gather + MFMA GEMM + bias.  Grid (144,4), 512 thr (8 waves).
// Block: 64 px x 128 oc, K=1152 in 9 kc-chunks.  Wave = 16-oc slice x 4 nt.
// ---------------------------------------------------------------------------
__global__ __launch_bounds__(512, 4) void dconv_kernel(
    const unsigned short* __restrict__ xt, const unsigned short* __restrict__ wbf,
    const float* __restrict__ bias, const float* __restrict__ om,
    float* __restrict__ out)
{
    __shared__ int sprep[576 * 8];          // 18432 B
    __shared__ int btile[64 * BT_STRIDE];   // 17408 B  (total 35840 B)

    const int t    = threadIdx.x;
    const int wave = __builtin_amdgcn_readfirstlane(t >> 6);
    const int lane = t & 63;
    const int quad = lane >> 4;
    const int m    = lane & 15;
    const int b    = blockIdx.y;
    const int p0   = blockIdx.x * 64;

    // ---- phase 1: sampling prep -------------------------------------------
    for (int s = t; s < 576; s += 512) {
        const int kc  = s >> 6;
        const int pxl = s & 63;
        const int pg  = p0 + pxl;
        const int h   = pg / 96;
        const int w   = pg - h * 96;
        const int ki  = kc / 3, kj = kc - 3 * (kc / 3);

        const float* omb = om + (size_t)b * 27 * HW + pg;
        const float o1 = omb[(size_t)kc * HW];
        const float o2 = omb[(size_t)(9 + kc) * HW];
        const float mr = omb[(size_t)(18 + kc) * HW];
        const float mk = 2.f / (1.f + __expf(-mr));   // sigmoid * MASK_SCALE

        const float py = (float)(h - 1 + ki) + o1;
        const float px = (float)(w - 1 + kj) + o2;
        const float y0f = floorf(py), x0f = floorf(px);
        const float ly = py - y0f,    lx = px - x0f;
        const int y0 = (int)y0f, x0 = (int)x0f;
        const int y1 = y0 + 1,   x1 = x0 + 1;

        const float w00 = (1.f - ly) * (1.f - lx), w01 = (1.f - ly) * lx;
        const float w10 = ly * (1.f - lx),         w11 = ly * lx;

        const int yc0 = min(max(y0, 0), HH - 1), yc1 = min(max(y1, 0), HH - 1);
        const int xc0 = min(max(x0, 0), WW - 1), xc1 = min(max(x1, 0), WW - 1);
        const bool vy0 = (y0 >= 0) && (y0 < HH), vy1 = (y1 >= 0) && (y1 < HH);
        const bool vx0 = (x0 >= 0) && (x0 < WW), vx1 = (x1 >= 0) && (x1 < WW);

        sprep[s * 8 + 0] = yc0 * 96 + xc0;
        sprep[s * 8 + 1] = yc0 * 96 + xc1;
        sprep[s * 8 + 2] = yc1 * 96 + xc0;
        sprep[s * 8 + 3] = yc1 * 96 + xc1;
        sprep[s * 8 + 4] = __builtin_bit_cast(int, (vy0 && vx0) ? mk * w00 : 0.f);
        sprep[s * 8 + 5] = __builtin_bit_cast(int, (vy0 && vx1) ? mk * w01 : 0.f);
        sprep[s * 8 + 6] = __builtin_bit_cast(int, (vy1 && vx0) ? mk * w10 : 0.f);
        sprep[s * 8 + 7] = __builtin_bit_cast(int, (vy1 && vx1) ? mk * w11 : 0.f);
    }
    __syncthreads();

    const unsigned short* xtb = xt + (size_t)b * HW * CIN_;

    float4v acc[4];
#pragma unroll
    for (int j = 0; j < 4; j++)
#pragma unroll
        for (int r = 0; r < 4; r++) acc[j][r] = 0.f;

    for (int kc = 0; kc < 9; kc++) {
        if (kc) __syncthreads();

        // ---- gather: wave-per-pixel, lane = 2 channels (bf16 pair = 4 B) --
#pragma unroll
        for (int p = 0; p < 8; p++) {
            const int pxl = p * 8 + wave;
            const int s   = kc * 64 + pxl;
            const int4   id4 = *(const int4*)&sprep[s * 8];
            const float4 w4  = *(const float4*)&sprep[s * 8 + 4];
            const unsigned u0 = *(const unsigned*)(xtb + (size_t)id4.x * CIN_ + 2 * lane);
            const unsigned u1 = *(const unsigned*)(xtb + (size_t)id4.y * CIN_ + 2 * lane);
            const unsigned u2 = *(const unsigned*)(xtb + (size_t)id4.z * CIN_ + 2 * lane);
            const unsigned u3 = *(const unsigned*)(xtb + (size_t)id4.w * CIN_ + 2 * lane);
            const float vx = w4.x * bflo(u0) + w4.y * bflo(u1) + w4.z * bflo(u2) + w4.w * bflo(u3);
            const float vy = w4.x * bfhi(u0) + w4.y * bfhi(u1) + w4.z * bfhi(u2) + w4.w * bfhi(u3);
            btile[pxl * BT_STRIDE + lane] =
                (int)((unsigned)f2bf(vx) | ((unsigned)f2bf(vy) << 16));
        }
        __syncthreads();

        // ---- MFMA: wave = 16-oc slice; 4 kst x 4 nt -----------------------
        const short* abase = (const short*)wbf + (size_t)(wave * 16 + m) * 1152 + kc * 128 + quad * 8;
#pragma unroll
        for (int kst = 0; kst < 4; kst++) {
            const short8v a = *(const short8v*)(abase + kst * 32);
#pragma unroll
            for (int nt = 0; nt < 4; nt++) {
                const short8v bf = *(const short8v*)((const short*)btile
                    + (nt * 16 + m) * (BT_STRIDE * 2) + kst * 32 + quad * 8);
                acc[nt] = __builtin_amdgcn_mfma_f32_16x16x32_bf16(a, bf, acc[nt], 0, 0, 0);
            }
        }
    }

    // ---- epilogue ---------------------------------------------------------
#pragma unroll
    for (int r = 0; r < 4; r++) {
        const int oc = wave * 16 + quad * 4 + r;
        const float bv = bias[oc];
#pragma unroll
        for (int nt = 0; nt < 4; nt++)
            out[(size_t)(b * COUT_ + oc) * HW + p0 + nt * 16 + m] = acc[nt][r] + bv;
    }
}

extern "C" void kernel_launch(void* const* d_in, const int* in_sizes, int n_in,
                              void* d_out, int out_size, void* d_ws, size_t ws_size,
                              hipStream_t stream) {
    const float* x      = (const float*)d_in[0];
    const float* weight = (const float*)d_in[1];
    const float* bias   = (const float*)d_in[2];
    const float* wom    = (const float*)d_in[3];

    float* out     = (float*)d_out;
    float* off_out = out + OUT_ELEMS;

    unsigned short* xtb  = (unsigned short*)((char*)d_ws + XT_OFF);
    float*          om   = (float*)((char*)d_ws + OM_OFF);
    unsigned short* wbf  = (unsigned short*)((char*)d_ws + WBF_OFF);
    unsigned short* womb = (unsigned short*)((char*)d_ws + WOMB_OFF);

    transpose_kernel<<<dim3(144, 4), 256, 0, stream>>>(x, xtb);
    wconv_kernel    <<<dim3(720),    256, 0, stream>>>(weight, wom, wbf, womb);
    om_gemm_kernel  <<<dim3(144, 4), 256, 0, stream>>>(xtb, womb, om, off_out);
    dconv_kernel    <<<dim3(144, 4), 512, 0, stream>>>(xtb, wbf, bias, om, out);
}